// Round 11
// baseline (100.313 us; speedup 1.0000x reference)
//
#include <hip/hip_runtime.h>
#include <math.h>

#define DIM   100
#define NV    64
#define BS    512
#define MAXCH 1664          // 128 combos * 13 chunks max, multiple of 128
#define SMW   108           // padded mask row stride (bytes)
#define SMH   103           // padded mask rows
#define SHWC  (0.5f / 255.0f)

// ---------------------------------------------------------------------------
// Fused kernel: one block per (batch, direction m). Mask staged as u8 in a
// CLAMP-PADDED 103x108 layout (row r = m[clamp(r-1)], col 3 / cols 104-105
// duplicate borders) -> bilinear gather = 4 ds_read_u8 at fixed immediate
// offsets, reproducing the ref's clip() exactly. Kept-sample direct
// enumeration (R7-R10, numerics verified): per combo binary-search exact last
// valid step T (bit-exact float exprs), K = cells crossed; per sample
// t = ceil((k+D)*rcp(|vu|) - 5e-3) + one-step fixup vs bit-exact floor(u(t)).
// prm = one b128 {x0,y0,vx,vy} + one b32 meta = sign*(K+0.5). 8-kept chunks,
// strided pool, ds_read_b64 entry quads. LDS ~17.3 KB -> 8 blocks/CU, 2048
// blocks fully co-resident. FINALIZE IS FUSED: blocks release-store |s| to
// ws, atomicAdd a per-batch counter (zeroed via hipMemsetAsync each call);
// the 4th arriver computes both polygon areas (wave 0) and writes iou[b].
// Bit-deterministic: which block finalizes varies, the values don't.
// ---------------------------------------------------------------------------
template<bool AX>
__device__ __forceinline__ float mainloop(
    const unsigned char* sm, const float4* prmA, const float* meta,
    const unsigned short* chunkTab, int totE, int tid) {
  const int grp = tid >> 5;                // 0..7
  const int sub = (tid >> 3) & 3;          // 0..3
  const int st  = tid & 7;                 // kept-sample index within chunk
  const int base0 = grp * 16 + sub * 4;
  float acc = 0.0f;

  for (int i = 0; i * 128 < totE; ++i) {
    const ushort4 ent = *reinterpret_cast<const ushort4*>(
        &chunkTab[i * 128 + base0]);       // one ds_read_b64 per 256 samples

    #define SAMPLE(e) {                                                    \
      const int c = (e) >> 4;                                              \
      const float kf = (float)((((e) & 15) << 3) | st);                    \
      const float4 p = prmA[c];            /* ds_read_b128 */              \
      const float mt = meta[c];            /* ds_read_b32  */              \
      const float vu = AX ? p.z : p.w;                                     \
      const float u0 = AX ? p.x : p.y;                                     \
      const float fu0 = floorf(u0);                                        \
      const float Bv = __builtin_amdgcn_rcpf(fabsf(vu));                   \
      const float D  = (vu > 0.0f) ? (fu0 - u0) : (u0 - fu0 - 1.0f);       \
      const float te = ceilf((kf + D) * Bv - 0.005f);                      \
      const float ck = fu0 + __builtin_copysignf(kf, vu);                  \
      const float u1 = __fadd_rn(__fmul_rn(te, vu), u0);                   \
      float t = (floorf(u1) == ck) ? te : (te + 1.0f);                     \
      t = fmaxf(t, 0.0f);                                                  \
      const float xs = __fadd_rn(__fmul_rn(t, p.z), p.x);                  \
      const float ys = __fadd_rn(__fmul_rn(t, p.w), p.y);                  \
      const float X0 = floorf(xs), Y0 = floorf(ys);                        \
      const float wx1 = xs - X0, wy1 = ys - Y0;                            \
      const float wx0 = 1.0f - wx1, wy0 = 1.0f - wy1;                      \
      const int ix = max(min((int)X0, 100), -1);                           \
      const int iy = max(min((int)Y0, 100), -1);                           \
      const int a = iy * SMW + ix;                                         \
      const float g00 = (float)sm[a + (SMW + 4)];                          \
      const float g10 = (float)sm[a + (SMW + 5)];                          \
      const float g01 = (float)sm[a + (2 * SMW + 4)];                      \
      const float g11 = (float)sm[a + (2 * SMW + 5)];                      \
      const float top = fmaf(wx1, g10, wx0 * g00);                         \
      const float bot = fmaf(wx1, g11, wx0 * g01);                         \
      const float val = fmaf(wy1, bot, wy0 * top);                         \
      const float w = (kf < fabsf(mt)) ? __builtin_copysignf(SHWC, mt)     \
                                       : 0.0f;                             \
      acc = fmaf(w, val, acc);                                             \
    }
    SAMPLE(ent.x); SAMPLE(ent.y); SAMPLE(ent.z); SAMPLE(ent.w);
    #undef SAMPLE
  }
  return acc;
}

__device__ __forceinline__ float wave_area(const float* P, int b, int v) {
  const float x0 = P[(size_t)(b * NV + v) * 2 + 0];
  const float y0 = P[(size_t)(b * NV + v) * 2 + 1];
  const int vn = (v + 1) & (NV - 1);
  const float x1 = P[(size_t)(b * NV + vn) * 2 + 0];
  const float y1 = P[(size_t)(b * NV + vn) * 2 + 1];
  float ym = y0;
  #pragma unroll
  for (int o = 32; o > 0; o >>= 1) ym = fmaxf(ym, __shfl_xor(ym, o, 64));
  float term = (x1 - x0) * (ym - (y1 + y0) * 0.5f);
  #pragma unroll
  for (int o = 32; o > 0; o >>= 1) term += __shfl_xor(term, o, 64);
  return fabsf(term);
}

template<bool FUSED>
__global__ __launch_bounds__(256, 8) void diffiou_intersect(
    const float* __restrict__ poly, const float* __restrict__ gt,
    const float* __restrict__ gt_mask,
    float* __restrict__ ws, int* __restrict__ cnt, float* __restrict__ out) {
  __shared__ unsigned char sm[SMH * SMW];        // 11124 B, clamp-padded
  __shared__ float4 prmA[128];                   // 2048 B: x0,y0,vx,vy
  __shared__ float  meta[128];                   // 512 B: sign*(K+0.5)
  __shared__ unsigned short chunkTab[MAXCH];     // 3328 B
  __shared__ int   wsum[2];
  __shared__ int   totalChunks;
  __shared__ float red[4];
  __shared__ int   flag;

  const int bid = blockIdx.x;
  const int b   = bid >> 2;
  const int m   = bid & 3;
  const bool ax = (m < 2);                 // DIRECTIONS = x,x,y,y
  const int tid = threadIdx.x;

  // ---- phase 1: stage clamp-padded u8 mask ----
  {
    const float* src = gt_mask + (size_t)(b * 4 + m) * (DIM * DIM);
    for (int j = tid; j < SMH * 25; j += 256) {
      const int r = j / 25;                // 0..102
      const int g = j - r * 25;            // 0..24
      const int sr = min(max(r - 1, 0), DIM - 1);
      const float4 v = *reinterpret_cast<const float4*>(&src[sr * DIM + 4 * g]);
      const unsigned int c0 = (unsigned int)__float2int_rn(v.x * 255.0f);
      const unsigned int c1 = (unsigned int)__float2int_rn(v.y * 255.0f);
      const unsigned int c2 = (unsigned int)__float2int_rn(v.z * 255.0f);
      const unsigned int c3 = (unsigned int)__float2int_rn(v.w * 255.0f);
      *reinterpret_cast<unsigned int*>(&sm[r * SMW + 4 + 4 * g]) =
          c0 | (c1 << 8) | (c2 << 16) | (c3 << 24);   // 4B-aligned
    }
    for (int r = tid; r < SMH; r += 256) { // border duplicates
      const int sr = min(max(r - 1, 0), DIM - 1);
      const unsigned char e0 =
          (unsigned char)__float2int_rn(src[sr * DIM + 0] * 255.0f);
      const unsigned char e9 =
          (unsigned char)__float2int_rn(src[sr * DIM + DIM - 1] * 255.0f);
      sm[r * SMW + 3] = e0;
      sm[r * SMW + 104] = e9;
      sm[r * SMW + 105] = e9;
    }
    for (int j = tid; j < MAXCH; j += 256) chunkTab[j] = 15;  // sentinel
  }

  // ---- per-combo setup ----
  int ncv = 0;
  if (tid < 128) {
    const int e  = tid >> 1;
    const int fb = tid & 1;
    const float* pb = poly + (size_t)b * NV * 2;
    const float ex0 = pb[e * 2 + 0], ey0 = pb[e * 2 + 1];
    const int   en  = (e + 1) & (NV - 1);
    const float ex1 = pb[en * 2 + 0], ey1 = pb[en * 2 + 1];
    const float sign = (ax ? (ex1 > ex0) : (ey1 > ey0)) ? 1.0f : -1.0f;
    const float x0 = fb ? ex1 : ex0, y0 = fb ? ey1 : ey0;
    const float x1 = fb ? ex0 : ex1, y1 = fb ? ey0 : ey1;
    float vx = (x1 - x0) + 1e-6f;
    float vy = (y1 - y0) + 1e-6f;
    const float n = __fsqrt_rn(__fadd_rn(__fmul_rn(vx, vx), __fmul_rn(vy, vy)));
    vx = __fdiv_rn(vx, n);
    vy = __fdiv_rn(vy, n);
    // bbox + tolerances; u-bound [0,99] folded into the axis coord (exact)
    float xlo = fminf(x0, x1) - 0.001f, xhi = fmaxf(x0, x1) + 0.001f;
    float ylo = fminf(y0, y1) - 0.001f, yhi = fmaxf(y0, y1) + 0.001f;
    if (ax) { xlo = fmaxf(xlo, 0.0f); xhi = fminf(xhi, (float)(DIM - 1)); }
    else    { ylo = fmaxf(ylo, 0.0f); yhi = fminf(yhi, (float)(DIM - 1)); }

    #define VALID_AT(tt, out_) {                                  \
      const float tf_ = (float)(tt);                              \
      const float xs_ = __fadd_rn(__fmul_rn(tf_, vx), x0);        \
      const float ys_ = __fadd_rn(__fmul_rn(tf_, vy), y0);        \
      out_ = (xs_ <= xhi) && (xs_ >= xlo) &&                      \
             (ys_ <= yhi) && (ys_ >= ylo);                        \
    }
    int T;
    bool v200; VALID_AT(200, v200);
    if (v200) { T = 200; }
    else {
      int lo = 0, hi = 200;
      #pragma unroll
      for (int it = 0; it < 8; ++it) {
        const int mid = (lo + hi) >> 1;
        bool vm; VALID_AT(mid, vm);
        if (vm) lo = mid; else hi = mid;
      }
      T = lo;
    }
    #undef VALID_AT

    const float vu  = ax ? vx : vy;
    const float u0  = ax ? x0 : y0;
    const float fu0 = floorf(u0);
    const float uT  = __fadd_rn(__fmul_rn((float)T, vu), u0);
    int K = abs((int)floorf(uT) - (int)fu0);
    K = min(K, 99);
    prmA[tid] = make_float4(x0, y0, vx, vy);
    meta[tid] = sign * ((float)K + 0.5f);
    ncv = (K >> 3) + 1;                    // 8-kept chunks, <= 13
  }

  // ---- prefix scan (2 waves) + scatter chunk table ----
  int v = ncv;
  #pragma unroll
  for (int i = 1; i < 64; i <<= 1) {
    const int w = __shfl_up(v, i, 64);
    if ((tid & 63) >= i) v += w;
  }
  if (((tid & 63) == 63) && (tid < 128)) wsum[tid >> 6] = v;
  __syncthreads();
  if ((tid >= 64) && (tid < 128)) v += wsum[0];
  if (tid < 128) {
    const int start = v - ncv;
    for (int k = 0; k < ncv; ++k)
      chunkTab[start + k] = (unsigned short)((tid << 4) | k);
    if (tid == 127) totalChunks = v;
  }
  __syncthreads();

  const int totE = totalChunks;
  const float acc = ax ? mainloop<true >(sm, prmA, meta, chunkTab, totE, tid)
                       : mainloop<false>(sm, prmA, meta, chunkTab, totE, tid);

  // ---- block reduce (4 waves) ----
  float a = acc;
  #pragma unroll
  for (int o = 32; o > 0; o >>= 1) a += __shfl_xor(a, o, 64);
  if ((tid & 63) == 0) red[tid >> 6] = a;
  __syncthreads();

  if (!FUSED) {
    if (tid == 0) ws[bid] = fabsf(red[0] + red[1] + red[2] + red[3]);
    return;
  }

  // ---- fused finalize: 4th arriver per batch computes iou ----
  if (tid == 0) {
    const float s = fabsf(red[0] + red[1] + red[2] + red[3]);
    __hip_atomic_store(&ws[bid], s, __ATOMIC_RELEASE,
                       __HIP_MEMORY_SCOPE_AGENT);
    const int old = __hip_atomic_fetch_add(&cnt[b], 1, __ATOMIC_ACQ_REL,
                                           __HIP_MEMORY_SCOPE_AGENT);
    flag = (old == 3);
  }
  __syncthreads();
  if (flag && tid < 64) {
    const float pa = wave_area(poly, b, tid);
    const float ga = wave_area(gt,   b, tid);
    if (tid == 0) {
      const float i0 = __hip_atomic_load(&ws[b * 4 + 0], __ATOMIC_ACQUIRE,
                                         __HIP_MEMORY_SCOPE_AGENT);
      const float i1 = __hip_atomic_load(&ws[b * 4 + 1], __ATOMIC_ACQUIRE,
                                         __HIP_MEMORY_SCOPE_AGENT);
      const float i2 = __hip_atomic_load(&ws[b * 4 + 2], __ATOMIC_ACQUIRE,
                                         __HIP_MEMORY_SCOPE_AGENT);
      const float i3 = __hip_atomic_load(&ws[b * 4 + 3], __ATOMIC_ACQUIRE,
                                         __HIP_MEMORY_SCOPE_AGENT);
      const float ia = 0.25f * (i0 + i1 + i2 + i3);
      out[b] = ia / (pa + ga - ia);
    }
  }
}

// Fallback finalize (only used if ws_size is too small for the counters).
__global__ __launch_bounds__(64) void diffiou_finalize(
    const float* __restrict__ poly, const float* __restrict__ gt,
    const float* __restrict__ ws, float* __restrict__ out) {
  const int b = blockIdx.x;
  const int v = threadIdx.x;
  const float pa = wave_area(poly, b, v);
  const float ga = wave_area(gt, b, v);
  if (v == 0) {
    const float ia = 0.25f * (ws[b * 4 + 0] + ws[b * 4 + 1] +
                              ws[b * 4 + 2] + ws[b * 4 + 3]);
    out[b] = ia / (pa + ga - ia);
  }
}

// ---------------------------------------------------------------------------
extern "C" void kernel_launch(void* const* d_in, const int* in_sizes, int n_in,
                              void* d_out, int out_size, void* d_ws, size_t ws_size,
                              hipStream_t stream) {
  const float* poly    = (const float*)d_in[0];
  const float* gt      = (const float*)d_in[1];
  const float* gt_mask = (const float*)d_in[2];
  float* out = (float*)d_out;
  float* ws  = (float*)d_ws;                       // 2048 floats: |s| slots
  int*   cnt = (int*)((char*)d_ws + 2048 * 4);     // 512 arrival counters

  if (ws_size >= 2048 * 4 + 512 * 4) {
    hipMemsetAsync(cnt, 0, 512 * sizeof(int), stream);
    hipLaunchKernelGGL((diffiou_intersect<true>), dim3(BS * 4), dim3(256), 0,
                       stream, poly, gt, gt_mask, ws, cnt, out);
  } else {
    hipLaunchKernelGGL((diffiou_intersect<false>), dim3(BS * 4), dim3(256), 0,
                       stream, poly, gt, gt_mask, ws, cnt, out);
    hipLaunchKernelGGL(diffiou_finalize, dim3(BS), dim3(64), 0, stream,
                       poly, gt, ws, out);
  }
}

// Round 12
// 43.461 us; speedup vs baseline: 2.3081x; 2.3081x over previous
//
#include <hip/hip_runtime.h>
#include <math.h>

#define DIM   100
#define NV    64
#define BS    512
#define MAXCH 1664          // 128 combos * 13 chunks max, multiple of 128
#define SMW   108           // padded mask row stride (bytes)
#define SMH   103           // padded mask rows
#define MSZ   (SMH * SMW)   // one padded mask slice (11124 B)

// ---------------------------------------------------------------------------
// One block per (batch, direction-PAIR). DIRECTIONS = [x,x,y,y]: slices
// (4b+0, 4b+1) share axis 'x' and (4b+2, 4b+3) share 'y' -> for a pair, the
// edges, sign, bbox, exact last-valid-step T, K, and chunk table are
// IDENTICAL; only the mask slice differs. One block stages BOTH masks
// (clamp-padded u8 103x108 layout, R10-proven: bilinear = 4 ds_read_u8 at
// fixed immediate offsets, exact clip() semantics) and runs ONE fused main
// loop: shared t/weights/address per sample + two gathers + two FMAs ->
// ~half the per-sample VALU of R10. Kept-sample direct enumeration as
// R7-R10 (bit-identical rounding): t = ceil(fmaf(kf,B,A')), one-step fixup
// vs bit-exact floor(u(t)). LDS ~29.8 KB -> grid 1024 = 4 blocks/CU fully
// co-resident. Finalize stays a separate tiny kernel (R11 lesson: fused
// agent-scope atomics cause an L2 writeback/invalidate storm).
// ---------------------------------------------------------------------------
template<bool AX>
__device__ __forceinline__ void mainloop(
    const unsigned char* sm, const float4* prmA, const float4* prmB,
    const unsigned short* chunkTab, int totE, int tid,
    float& acc0o, float& acc1o) {
  const int grp = tid >> 5;                // 0..7
  const int sub = (tid >> 3) & 3;          // 0..3
  const int st  = tid & 7;                 // kept-sample index within chunk
  const int base0 = grp * 16 + sub * 4;
  float acc0 = 0.0f, acc1 = 0.0f;

  for (int i = 0; i * 128 < totE; ++i) {
    const ushort4 ent = *reinterpret_cast<const ushort4*>(
        &chunkTab[i * 128 + base0]);       // one ds_read_b64 per 256 pairs

    // p = {x0,y0,vx,vy}; q = {shw, Kf, B, A'}
    #define SAMPLE(e) {                                                    \
      const int c = (e) >> 4;                                              \
      const float kf = (float)((((e) & 15) << 3) | st);                    \
      const float4 p = prmA[c];                                            \
      const float4 q = prmB[c];                                            \
      const float vu = AX ? p.z : p.w;                                     \
      const float u0 = AX ? p.x : p.y;                                     \
      const float fu0 = floorf(u0);                                        \
      const float ck = fu0 + __builtin_copysignf(kf, vu);                  \
      const float te = ceilf(fmaf(kf, q.z, q.w));                          \
      const float u1 = __fadd_rn(__fmul_rn(te, vu), u0);                   \
      float t = (floorf(u1) == ck) ? te : (te + 1.0f);                     \
      t = fmaxf(t, 0.0f);                                                  \
      const float xs = __fadd_rn(__fmul_rn(t, p.z), p.x);                  \
      const float ys = __fadd_rn(__fmul_rn(t, p.w), p.y);                  \
      const float X0 = floorf(xs), Y0 = floorf(ys);                        \
      const float wx1 = xs - X0, wy1 = ys - Y0;                            \
      const float wx0 = 1.0f - wx1, wy0 = 1.0f - wy1;                      \
      const int ix = max(min((int)X0, 100), -1);                           \
      const int iy = max(min((int)Y0, 100), -1);                           \
      const int a = iy * SMW + ix;                                         \
      const float g00a = (float)sm[a + (SMW + 4)];                         \
      const float g10a = (float)sm[a + (SMW + 5)];                         \
      const float g01a = (float)sm[a + (2 * SMW + 4)];                     \
      const float g11a = (float)sm[a + (2 * SMW + 5)];                     \
      const float g00b = (float)sm[a + (MSZ + SMW + 4)];                   \
      const float g10b = (float)sm[a + (MSZ + SMW + 5)];                   \
      const float g01b = (float)sm[a + (MSZ + 2 * SMW + 4)];               \
      const float g11b = (float)sm[a + (MSZ + 2 * SMW + 5)];               \
      const float topa = fmaf(wx1, g10a, wx0 * g00a);                      \
      const float bota = fmaf(wx1, g11a, wx0 * g01a);                      \
      const float vala = fmaf(wy1, bota, wy0 * topa);                      \
      const float topb = fmaf(wx1, g10b, wx0 * g00b);                      \
      const float botb = fmaf(wx1, g11b, wx0 * g01b);                      \
      const float valb = fmaf(wy1, botb, wy0 * topb);                      \
      const float w = (kf <= q.y) ? q.x : 0.0f;                            \
      acc0 = fmaf(w, vala, acc0);                                          \
      acc1 = fmaf(w, valb, acc1);                                          \
    }
    SAMPLE(ent.x); SAMPLE(ent.y); SAMPLE(ent.z); SAMPLE(ent.w);
    #undef SAMPLE
  }
  acc0o = acc0; acc1o = acc1;
}

__global__ __launch_bounds__(256, 4) void diffiou_intersect(
    const float* __restrict__ poly, const float* __restrict__ gt_mask,
    float* __restrict__ ws) {
  __shared__ unsigned char sm[2 * MSZ];          // 22248 B, two padded masks
  __shared__ float4 prmA[128];                   // 2048 B: x0,y0,vx,vy
  __shared__ float4 prmB[128];                   // 2048 B: shw,Kf,B,A'
  __shared__ unsigned short chunkTab[MAXCH];     // 3328 B
  __shared__ int   wsum[2];
  __shared__ int   totalChunks;
  __shared__ float red[4][2];

  const int g   = blockIdx.x;              // 0..1023
  const int b   = g >> 1;
  const int mb  = (g & 1) * 2;             // 0 -> slices {0,1}, 1 -> {2,3}
  const bool ax = (mb == 0);               // DIRECTIONS = x,x,y,y
  const int tid = threadIdx.x;

  // ---- phase 1: stage BOTH clamp-padded u8 masks ----
  #pragma unroll
  for (int s = 0; s < 2; ++s) {
    const float* src = gt_mask + (size_t)(b * 4 + mb + s) * (DIM * DIM);
    unsigned char* dst = sm + s * MSZ;
    for (int j = tid; j < SMH * 25; j += 256) {
      const int r = j / 25;                // 0..102
      const int q = j - r * 25;            // 0..24
      const int sr = min(max(r - 1, 0), DIM - 1);
      const float4 v = *reinterpret_cast<const float4*>(&src[sr * DIM + 4 * q]);
      const unsigned int c0 = (unsigned int)__float2int_rn(v.x * 255.0f);
      const unsigned int c1 = (unsigned int)__float2int_rn(v.y * 255.0f);
      const unsigned int c2 = (unsigned int)__float2int_rn(v.z * 255.0f);
      const unsigned int c3 = (unsigned int)__float2int_rn(v.w * 255.0f);
      *reinterpret_cast<unsigned int*>(&dst[r * SMW + 4 + 4 * q]) =
          c0 | (c1 << 8) | (c2 << 16) | (c3 << 24);   // 4B-aligned
    }
    for (int r = tid; r < SMH; r += 256) { // border duplicates
      const int sr = min(max(r - 1, 0), DIM - 1);
      const unsigned char e0 =
          (unsigned char)__float2int_rn(src[sr * DIM + 0] * 255.0f);
      const unsigned char e9 =
          (unsigned char)__float2int_rn(src[sr * DIM + DIM - 1] * 255.0f);
      dst[r * SMW + 3] = e0;
      dst[r * SMW + 104] = e9;
      dst[r * SMW + 105] = e9;
    }
  }
  for (int j = tid; j < MAXCH; j += 256) chunkTab[j] = 15;  // sentinel

  // ---- per-combo setup (shared by both slices of the pair) ----
  int ncv = 0;
  if (tid < 128) {
    const int e  = tid >> 1;
    const int fb = tid & 1;
    const float* pb = poly + (size_t)b * NV * 2;
    const float ex0 = pb[e * 2 + 0], ey0 = pb[e * 2 + 1];
    const int   en  = (e + 1) & (NV - 1);
    const float ex1 = pb[en * 2 + 0], ey1 = pb[en * 2 + 1];
    const float sign = (ax ? (ex1 > ex0) : (ey1 > ey0)) ? 1.0f : -1.0f;
    const float x0 = fb ? ex1 : ex0, y0 = fb ? ey1 : ey0;
    const float x1 = fb ? ex0 : ex1, y1 = fb ? ey0 : ey1;
    float vx = (x1 - x0) + 1e-6f;
    float vy = (y1 - y0) + 1e-6f;
    const float n = __fsqrt_rn(__fadd_rn(__fmul_rn(vx, vx), __fmul_rn(vy, vy)));
    vx = __fdiv_rn(vx, n);
    vy = __fdiv_rn(vy, n);
    // bbox + tolerances; u-bound [0,99] folded into the axis coord (exact)
    float xlo = fminf(x0, x1) - 0.001f, xhi = fmaxf(x0, x1) + 0.001f;
    float ylo = fminf(y0, y1) - 0.001f, yhi = fmaxf(y0, y1) + 0.001f;
    if (ax) { xlo = fmaxf(xlo, 0.0f); xhi = fminf(xhi, (float)(DIM - 1)); }
    else    { ylo = fmaxf(ylo, 0.0f); yhi = fminf(yhi, (float)(DIM - 1)); }

    #define VALID_AT(tt, out_) {                                  \
      const float tf_ = (float)(tt);                              \
      const float xs_ = __fadd_rn(__fmul_rn(tf_, vx), x0);        \
      const float ys_ = __fadd_rn(__fmul_rn(tf_, vy), y0);        \
      out_ = (xs_ <= xhi) && (xs_ >= xlo) &&                      \
             (ys_ <= yhi) && (ys_ >= ylo);                        \
    }
    int T;
    bool v200; VALID_AT(200, v200);
    if (v200) { T = 200; }
    else {
      int lo = 0, hi = 200;
      #pragma unroll
      for (int it = 0; it < 8; ++it) {
        const int mid = (lo + hi) >> 1;
        bool vm; VALID_AT(mid, vm);
        if (vm) lo = mid; else hi = mid;
      }
      T = lo;
    }
    #undef VALID_AT

    const float vu  = ax ? vx : vy;
    const float u0  = ax ? x0 : y0;
    const float fu0 = floorf(u0);
    const float uT  = __fadd_rn(__fmul_rn((float)T, vu), u0);
    int K = abs((int)floorf(uT) - (int)fu0);
    K = min(K, 99);
    const float B = __fdiv_rn(1.0f, fabsf(vu));
    const float D = (vu > 0.0f) ? (fu0 - u0) : (u0 - fu0 - 1.0f);
    prmA[tid] = make_float4(x0, y0, vx, vy);
    prmB[tid] = make_float4(sign * (0.5f / 255.0f), (float)K,
                            B, fmaf(D, B, -0.005f));
    ncv = (K >> 3) + 1;                    // 8-kept chunks, <= 13
  }

  // ---- prefix scan (2 waves) + scatter chunk table ----
  int v = ncv;
  #pragma unroll
  for (int i = 1; i < 64; i <<= 1) {
    const int w = __shfl_up(v, i, 64);
    if ((tid & 63) >= i) v += w;
  }
  if (((tid & 63) == 63) && (tid < 128)) wsum[tid >> 6] = v;
  __syncthreads();
  if ((tid >= 64) && (tid < 128)) v += wsum[0];
  if (tid < 128) {
    const int start = v - ncv;
    for (int k = 0; k < ncv; ++k)
      chunkTab[start + k] = (unsigned short)((tid << 4) | k);
    if (tid == 127) totalChunks = v;
  }
  __syncthreads();

  const int totE = totalChunks;
  float acc0, acc1;
  if (ax) mainloop<true >(sm, prmA, prmB, chunkTab, totE, tid, acc0, acc1);
  else    mainloop<false>(sm, prmA, prmB, chunkTab, totE, tid, acc0, acc1);

  // ---- block reduce (4 waves), both accumulators ----
  #pragma unroll
  for (int o = 32; o > 0; o >>= 1) {
    acc0 += __shfl_xor(acc0, o, 64);
    acc1 += __shfl_xor(acc1, o, 64);
  }
  if ((tid & 63) == 0) { red[tid >> 6][0] = acc0; red[tid >> 6][1] = acc1; }
  __syncthreads();
  if (tid == 0) {
    const float s0 = red[0][0] + red[1][0] + red[2][0] + red[3][0];
    const float s1 = red[0][1] + red[1][1] + red[2][1] + red[3][1];
    ws[b * 4 + mb + 0] = fabsf(s0);
    ws[b * 4 + mb + 1] = fabsf(s1);
  }
}

// ---------------------------------------------------------------------------
// Kernel 2: per-batch areas + final IoU. One wave per batch.
// ---------------------------------------------------------------------------
__device__ __forceinline__ float wave_area(const float* P, int b, int v) {
  const float x0 = P[(size_t)(b * NV + v) * 2 + 0];
  const float y0 = P[(size_t)(b * NV + v) * 2 + 1];
  const int vn = (v + 1) & (NV - 1);
  const float x1 = P[(size_t)(b * NV + vn) * 2 + 0];
  const float y1 = P[(size_t)(b * NV + vn) * 2 + 1];
  float ym = y0;
  #pragma unroll
  for (int o = 32; o > 0; o >>= 1) ym = fmaxf(ym, __shfl_xor(ym, o, 64));
  float term = (x1 - x0) * (ym - (y1 + y0) * 0.5f);
  #pragma unroll
  for (int o = 32; o > 0; o >>= 1) term += __shfl_xor(term, o, 64);
  return fabsf(term);
}

__global__ __launch_bounds__(64) void diffiou_finalize(
    const float* __restrict__ poly, const float* __restrict__ gt,
    const float* __restrict__ ws, float* __restrict__ out) {
  const int b = blockIdx.x;
  const int v = threadIdx.x;
  const float pa = wave_area(poly, b, v);
  const float ga = wave_area(gt, b, v);
  if (v == 0) {
    const float ia = 0.25f * (ws[b * 4 + 0] + ws[b * 4 + 1] +
                              ws[b * 4 + 2] + ws[b * 4 + 3]);
    out[b] = ia / (pa + ga - ia);
  }
}

// ---------------------------------------------------------------------------
extern "C" void kernel_launch(void* const* d_in, const int* in_sizes, int n_in,
                              void* d_out, int out_size, void* d_ws, size_t ws_size,
                              hipStream_t stream) {
  const float* poly    = (const float*)d_in[0];
  const float* gt      = (const float*)d_in[1];
  const float* gt_mask = (const float*)d_in[2];
  float* out = (float*)d_out;
  float* ws  = (float*)d_ws;   // 2048 floats: |s| per (batch, direction)

  hipLaunchKernelGGL(diffiou_intersect, dim3(BS * 2), dim3(256), 0, stream,
                     poly, gt_mask, ws);
  hipLaunchKernelGGL(diffiou_finalize, dim3(BS), dim3(64), 0, stream,
                     poly, gt, ws, out);
}